// Round 5
// baseline (116.519 us; speedup 1.0000x reference)
//
#include <hip/hip_runtime.h>

// DepthwiseMultiScaleFIR: 4 causal depthwise convs (k=3,7,15,31), fused.
// x: [B=4, L=4096, C=2048] fp32 (channel innermost). w_k: [C, 1, k].
// y_k[b,t,c] = sum_j w_k[c,j] * x[b, t-(k-1)+j, c]
//
// v5: v4 (float2 = 2 ch/thread, register sliding window, NT stores) + explicit
// x-tile double-buffer: next tile's 8 loads issue into temp regs BEFORE the
// current tile's compute, breaking the xs[] anti-dependency so HBM latency
// hides under the ~1800-cyc FMA phase within one wave (we only have 2
// waves/SIMD at ~225 VGPR, so intra-wave ILP matters).

#define BB 4
#define LL 4096
#define CC 2048
#define TT 8       // timesteps per inner iteration
#define HALO 30    // max kernel size - 1
#define STRIP 128  // timesteps per block
#define NIT (STRIP / TT)

typedef float v2f __attribute__((ext_vector_type(2)));

__global__ __launch_bounds__(256) void fir_fused_f2(
    const float* __restrict__ x,
    const float* __restrict__ w0, const float* __restrict__ w1,
    const float* __restrict__ w2, const float* __restrict__ w3,
    float* __restrict__ out)
{
    const int c0 = blockIdx.x * 512 + threadIdx.x * 2;  // 2 adjacent channels
    const int tb = blockIdx.y * STRIP;
    const int b  = blockIdx.z;

    const long long bbase = (long long)b * LL * CC + c0;
    const float* __restrict__ xb = x + bbase;           // per-thread base; t*CC fits int32

    const long long N = (long long)BB * LL * CC;
    float* __restrict__ o0 = out + bbase;
    float* __restrict__ o1 = out + N + bbase;
    float* __restrict__ o2 = out + 2 * N + bbase;
    float* __restrict__ o3 = out + 3 * N + bbase;

    // --- weights for both channels into registers
    v2f a0[3], a1[7], a2[15], a3[31];
#pragma unroll
    for (int j = 0; j < 3;  ++j) { a0[j].x = w0[c0 * 3  + j]; a0[j].y = w0[(c0 + 1) * 3  + j]; }
#pragma unroll
    for (int j = 0; j < 7;  ++j) { a1[j].x = w1[c0 * 7  + j]; a1[j].y = w1[(c0 + 1) * 7  + j]; }
#pragma unroll
    for (int j = 0; j < 15; ++j) { a2[j].x = w2[c0 * 15 + j]; a2[j].y = w2[(c0 + 1) * 15 + j]; }
#pragma unroll
    for (int j = 0; j < 31; ++j) { a3[j].x = w3[c0 * 31 + j]; a3[j].y = w3[(c0 + 1) * 31 + j]; }

    // --- prologue: halo window [tb-30, tb) + first tile [tb, tb+TT)
    v2f xs[HALO + TT];
#pragma unroll
    for (int j = 0; j < HALO; ++j) {
        const int t = tb - HALO + j;
        xs[j] = (t >= 0) ? *reinterpret_cast<const v2f*>(xb + (long long)t * CC)
                         : (v2f)(0.0f);
    }
#pragma unroll
    for (int j = 0; j < TT; ++j)
        xs[HALO + j] = *reinterpret_cast<const v2f*>(xb + (long long)(tb + j) * CC);

    for (int it = 0; it < NIT; ++it) {
        const int t0 = tb + it * TT;

        // --- prefetch NEXT tile into temp regs (issued before compute so the
        // HBM latency hides under the FMA phase). Last iter: reload current
        // tile (uniform select, valid addresses, L2-hot — negligible).
        const int tn = (it + 1 < NIT) ? (t0 + TT) : t0;
        v2f nx[TT];
#pragma unroll
        for (int j = 0; j < TT; ++j)
            nx[j] = *reinterpret_cast<const v2f*>(xb + (long long)(tn + j) * CC);

        // --- compute + stream out current tile
#pragma unroll
        for (int t = 0; t < TT; ++t) {
            v2f y0 = (v2f)(0.f), y1 = (v2f)(0.f), y2 = (v2f)(0.f), y3 = (v2f)(0.f);
#pragma unroll
            for (int j = 0; j < 31; ++j) y3 += a3[j] * xs[t + j];
#pragma unroll
            for (int j = 0; j < 15; ++j) y2 += a2[j] * xs[t + 16 + j];
#pragma unroll
            for (int j = 0; j < 7;  ++j) y1 += a1[j] * xs[t + 24 + j];
#pragma unroll
            for (int j = 0; j < 3;  ++j) y0 += a0[j] * xs[t + 28 + j];

            const int off = (t0 + t) * CC;   // < 33.5M, fits int32
            __builtin_nontemporal_store(y0, reinterpret_cast<v2f*>(o0 + off));
            __builtin_nontemporal_store(y1, reinterpret_cast<v2f*>(o1 + off));
            __builtin_nontemporal_store(y2, reinterpret_cast<v2f*>(o2 + off));
            __builtin_nontemporal_store(y3, reinterpret_cast<v2f*>(o3 + off));
        }

        // --- slide window forward by TT, then append prefetched tile
#pragma unroll
        for (int j = 0; j < HALO; ++j) xs[j] = xs[TT + j];
#pragma unroll
        for (int j = 0; j < TT; ++j) xs[HALO + j] = nx[j];
    }
}

extern "C" void kernel_launch(void* const* d_in, const int* in_sizes, int n_in,
                              void* d_out, int out_size, void* d_ws, size_t ws_size,
                              hipStream_t stream)
{
    const float* x  = (const float*)d_in[0];
    const float* w0 = (const float*)d_in[1];
    const float* w1 = (const float*)d_in[2];
    const float* w2 = (const float*)d_in[3];
    const float* w3 = (const float*)d_in[4];
    float* out = (float*)d_out;

    dim3 grid(CC / 512, LL / STRIP, BB);  // (4, 32, 4) = 512 blocks
    dim3 block(256);
    hipLaunchKernelGGL(fir_fused_f2, grid, block, 0, stream,
                       x, w0, w1, w2, w3, out);
}

// Round 6
// 109.274 us; speedup vs baseline: 1.0663x; 1.0663x over previous
//
#include <hip/hip_runtime.h>

// DepthwiseMultiScaleFIR: 4 causal depthwise convs (k=3,7,15,31), fused.
// x: [B=4, L=4096, C=2048] fp32 (channel innermost). w_k: [C, 1, k].
// y_k[b,t,c] = sum_j w_k[c,j] * x[b, t-(k-1)+j, c]
//
// v6 = v4 revert (best known: 111.7 us) + int32 offset addressing from v5.
// 2 channels/thread via clang ext_vector float2 (8 B/lane -> 512 B/wave),
// register sliding window (HALO=30 + TT=8), nontemporal stores so the 537 MB
// write stream doesn't evict x from L2/L3. Each block: 512 channels x
// 128-timestep strip. 512 blocks, ~2 waves/SIMD.
// v5's explicit double-buffer REGRESSED (116.5): compiler + 2-wave TLP already
// hides load latency; the extra register copies were pure overhead.

#define BB 4
#define LL 4096
#define CC 2048
#define TT 8       // timesteps per inner iteration
#define HALO 30    // max kernel size - 1
#define STRIP 128  // timesteps per block
#define NIT (STRIP / TT)

typedef float v2f __attribute__((ext_vector_type(2)));

__global__ __launch_bounds__(256) void fir_fused_f2(
    const float* __restrict__ x,
    const float* __restrict__ w0, const float* __restrict__ w1,
    const float* __restrict__ w2, const float* __restrict__ w3,
    float* __restrict__ out)
{
    const int c0 = blockIdx.x * 512 + threadIdx.x * 2;  // 2 adjacent channels
    const int tb = blockIdx.y * STRIP;
    const int b  = blockIdx.z;

    const long long bbase = (long long)b * LL * CC + c0;
    const float* __restrict__ xb = x + bbase;           // per-thread base; t*CC fits int32

    const long long N = (long long)BB * LL * CC;
    float* __restrict__ o0 = out + bbase;
    float* __restrict__ o1 = out + N + bbase;
    float* __restrict__ o2 = out + 2 * N + bbase;
    float* __restrict__ o3 = out + 3 * N + bbase;

    // --- weights for both channels into registers
    v2f a0[3], a1[7], a2[15], a3[31];
#pragma unroll
    for (int j = 0; j < 3;  ++j) { a0[j].x = w0[c0 * 3  + j]; a0[j].y = w0[(c0 + 1) * 3  + j]; }
#pragma unroll
    for (int j = 0; j < 7;  ++j) { a1[j].x = w1[c0 * 7  + j]; a1[j].y = w1[(c0 + 1) * 7  + j]; }
#pragma unroll
    for (int j = 0; j < 15; ++j) { a2[j].x = w2[c0 * 15 + j]; a2[j].y = w2[(c0 + 1) * 15 + j]; }
#pragma unroll
    for (int j = 0; j < 31; ++j) { a3[j].x = w3[c0 * 31 + j]; a3[j].y = w3[(c0 + 1) * 31 + j]; }

    // --- prologue: halo window [tb-30, tb)
    v2f xs[HALO + TT];
#pragma unroll
    for (int j = 0; j < HALO; ++j) {
        const int t = tb - HALO + j;
        xs[j] = (t >= 0) ? *reinterpret_cast<const v2f*>(xb + (long long)t * CC)
                         : (v2f)(0.0f);
    }

    for (int it = 0; it < NIT; ++it) {
        const int t0 = tb + it * TT;

        // load TT new timesteps (coalesced 512 B/wave each)
#pragma unroll
        for (int j = 0; j < TT; ++j)
            xs[HALO + j] = *reinterpret_cast<const v2f*>(xb + (t0 + j) * CC);

        // compute + stream out
#pragma unroll
        for (int t = 0; t < TT; ++t) {
            v2f y0 = (v2f)(0.f), y1 = (v2f)(0.f), y2 = (v2f)(0.f), y3 = (v2f)(0.f);
#pragma unroll
            for (int j = 0; j < 31; ++j) y3 += a3[j] * xs[t + j];
#pragma unroll
            for (int j = 0; j < 15; ++j) y2 += a2[j] * xs[t + 16 + j];
#pragma unroll
            for (int j = 0; j < 7;  ++j) y1 += a1[j] * xs[t + 24 + j];
#pragma unroll
            for (int j = 0; j < 3;  ++j) y0 += a0[j] * xs[t + 28 + j];

            const int off = (t0 + t) * CC;   // < 33.5M, fits int32
            __builtin_nontemporal_store(y0, reinterpret_cast<v2f*>(o0 + off));
            __builtin_nontemporal_store(y1, reinterpret_cast<v2f*>(o1 + off));
            __builtin_nontemporal_store(y2, reinterpret_cast<v2f*>(o2 + off));
            __builtin_nontemporal_store(y3, reinterpret_cast<v2f*>(o3 + off));
        }

        // slide window: carry last HALO values forward (register moves)
#pragma unroll
        for (int j = 0; j < HALO; ++j) xs[j] = xs[TT + j];
    }
}

extern "C" void kernel_launch(void* const* d_in, const int* in_sizes, int n_in,
                              void* d_out, int out_size, void* d_ws, size_t ws_size,
                              hipStream_t stream)
{
    const float* x  = (const float*)d_in[0];
    const float* w0 = (const float*)d_in[1];
    const float* w1 = (const float*)d_in[2];
    const float* w2 = (const float*)d_in[3];
    const float* w3 = (const float*)d_in[4];
    float* out = (float*)d_out;

    dim3 grid(CC / 512, LL / STRIP, BB);  // (4, 32, 4) = 512 blocks
    dim3 block(256);
    hipLaunchKernelGGL(fir_fused_f2, grid, block, 0, stream,
                       x, w0, w1, w2, w3, out);
}